// Round 4
// baseline (270.572 us; speedup 1.0000x reference)
//
#include <hip/hip_runtime.h>
#include <hip/hip_bf16.h>

// ROI Align (torchvision semantics), fp32 in/out, two-phase with BF16 staging:
//   Phase 1: NCHW fp32 -> NHWC bf16 transpose (nontemporal float4 loads,
//            ushort4 stores).
//   Phase 2: gather; grid (R, 2): block = 512 thr = HALF an ROI (128 ch).
//            16-lane groups, lane = 8 channels (uint4 tap = 16 B/lane).
//            32 groups/block; group g owns cell g and (if g<17) cell g+32
//            -> <=2 cells/thread. Tap loads software-pipelined at
//            iy-half-batch granularity (8 x uint4 = 32 VGPR each):
//            LA0, LA1, MA0, LB0, MA1, LB1, MB0, MB1 -> ~2 batches always
//            in flight; __launch_bounds__(512,4) caps VGPR at 128 so
//            2 blocks/CU (4 waves/SIMD) co-reside with 28.7 KB LDS.
//            BRANCHLESS taps (clamped indices always in-range), invalid
//            samples zeroed by weight.
//            LDS write swizzle cell ^ ((c>>3)&7) -> <=4-way banked.
//            Flush = contiguous nontemporal float4 (6272 floats/block).
// Fallback: if ws_size too small, round-1 NCHW fp32 kernel (exact).

constexpr int N_B  = 2;
constexpr int C_CH = 256;
constexpr int C_HALF = 128;
constexpr int H_F  = 200;
constexpr int W_F  = 304;
constexpr int HW   = H_F * W_F;        // 60800 = 64 * 950
constexpr int PH   = 7;
constexpr int PW   = 7;
constexpr int CELLS = PH * PW;         // 49
constexpr int CSTRIDE = 56;            // padded cell stride; holds cell^7 <= 55
constexpr float SCALE = 0.25f;

// native vector types for nontemporal builtins (HIP_vector_type rejected)
typedef float  v4f __attribute__((ext_vector_type(4)));

static __device__ __forceinline__ unsigned short f2bf(float f) {
    __hip_bfloat16 h = __float2bfloat16(f);   // round-to-nearest-even
    return *reinterpret_cast<unsigned short*>(&h);
}
static __device__ __forceinline__ float blo(unsigned int u) {
    return __uint_as_float(u << 16);          // even channel (low short)
}
static __device__ __forceinline__ float bhi(unsigned int u) {
    return __uint_as_float(u & 0xffff0000u);  // odd channel (high short)
}

// ---------------- Phase 1: NCHW fp32 -> NHWC bf16 ----------------
// grid (HW/64=950, C/64=4, N=2), block 256.
__global__ __launch_bounds__(256) void transpose_nchw_nhwc_bf16(
    const float* __restrict__ in, unsigned short* __restrict__ out)
{
    __shared__ float tile[64][65];
    int tx = blockIdx.x * 64;          // HW base
    int ty = blockIdx.y * 64;          // C base
    int n  = blockIdx.z;
    const float* ip = in  + (size_t)n * C_CH * HW;
    unsigned short* op = out + (size_t)n * HW * C_CH;

    int w4 = threadIdx.x & 15;         // HW quad index
    int cr = threadIdx.x >> 4;         // 0..15
#pragma unroll
    for (int p = 0; p < 4; ++p) {
        int c = p * 16 + cr;
        // read-once: bypass-cache hint keeps LLC space for the bf16 buffer
        v4f v = __builtin_nontemporal_load(
            (const v4f*)&ip[(size_t)(ty + c) * HW + tx + 4 * w4]);
        tile[c][4 * w4 + 0] = v.x;
        tile[c][4 * w4 + 1] = v.y;
        tile[c][4 * w4 + 2] = v.z;
        tile[c][4 * w4 + 3] = v.w;
    }
    __syncthreads();
    int cq = threadIdx.x & 15;         // channel quad index
    int hr = threadIdx.x >> 4;         // 0..15
#pragma unroll
    for (int p = 0; p < 4; ++p) {
        int hw = p * 16 + hr;
        ushort4 v;
        v.x = f2bf(tile[4 * cq + 0][hw]);
        v.y = f2bf(tile[4 * cq + 1][hw]);
        v.z = f2bf(tile[4 * cq + 2][hw]);
        v.w = f2bf(tile[4 * cq + 3][hw]);
        *(ushort4*)&op[(size_t)(tx + hw) * C_CH + ty + 4 * cq] = v;
    }
}

// ---------------- gather helpers ----------------
struct Geom {
    int   yl[2], yh[2]; float fy[2], vy[2];
    int   xl[2], xh[2]; float fx[2], vx[2];
};

static __device__ __forceinline__ void geom_cell(
    Geom& g, int cell, float x1, float y1, float bin_w, float bin_h)
{
    int ph = cell / PW;
    int pw = cell - ph * PW;
#pragma unroll
    for (int iy = 0; iy < 2; ++iy) {
        float y = y1 + ((float)ph + (iy ? 0.75f : 0.25f)) * bin_h;
        g.vy[iy] = (y >= -1.0f && y <= (float)H_F) ? 1.0f : 0.0f;
        float cy = fmaxf(y, 0.0f);
        int ylr = (int)floorf(cy);
        bool e = (ylr >= H_F - 1);
        g.yl[iy] = e ? H_F - 1 : ylr;
        g.yh[iy] = e ? H_F - 1 : ylr + 1;
        g.fy[iy] = e ? 0.0f : cy - (float)ylr;
    }
#pragma unroll
    for (int ix = 0; ix < 2; ++ix) {
        float x = x1 + ((float)pw + (ix ? 0.75f : 0.25f)) * bin_w;
        g.vx[ix] = (x >= -1.0f && x <= (float)W_F) ? 1.0f : 0.0f;
        float cx = fmaxf(x, 0.0f);
        int xlr = (int)floorf(cx);
        bool e = (xlr >= W_F - 1);
        g.xl[ix] = e ? W_F - 1 : xlr;
        g.xh[ix] = e ? W_F - 1 : xlr + 1;
        g.fx[ix] = e ? 0.0f : cx - (float)xlr;
    }
}

// one iy half-batch: 8 x uint4 taps (rl: xl0,xh0,xl1,xh1; rh: same)
static __device__ __forceinline__ void load_batch(
    uint4 t[8], const unsigned short* fb, const Geom& g, int iy)
{
    const unsigned short* rl = fb + (size_t)(g.yl[iy] * W_F) * C_CH;
    const unsigned short* rh = fb + (size_t)(g.yh[iy] * W_F) * C_CH;
    t[0] = *(const uint4*)(rl + (size_t)g.xl[0] * C_CH);
    t[1] = *(const uint4*)(rl + (size_t)g.xh[0] * C_CH);
    t[2] = *(const uint4*)(rl + (size_t)g.xl[1] * C_CH);
    t[3] = *(const uint4*)(rl + (size_t)g.xh[1] * C_CH);
    t[4] = *(const uint4*)(rh + (size_t)g.xl[0] * C_CH);
    t[5] = *(const uint4*)(rh + (size_t)g.xh[0] * C_CH);
    t[6] = *(const uint4*)(rh + (size_t)g.xl[1] * C_CH);
    t[7] = *(const uint4*)(rh + (size_t)g.xh[1] * C_CH);
}

// --- bilinear accumulate: 8 channels packed in uint4 (2 bf16 per uint) ---
static __device__ __forceinline__ void acc8(
    float* acc, uint4 ll, uint4 lh, uint4 hl, uint4 hh,
    float fxx, float fyy, float w)
{
#define ACC_PAIR(C, I0, I1)                                                   \
    { float a = blo(ll.C), b = blo(lh.C), c = blo(hl.C), d = blo(hh.C);       \
      float lo = a + fxx * (b - a), hi = c + fxx * (d - c);                   \
      acc[I0] += w * (lo + fyy * (hi - lo)); }                                \
    { float a = bhi(ll.C), b = bhi(lh.C), c = bhi(hl.C), d = bhi(hh.C);       \
      float lo = a + fxx * (b - a), hi = c + fxx * (d - c);                   \
      acc[I1] += w * (lo + fyy * (hi - lo)); }
    ACC_PAIR(x, 0, 1)
    ACC_PAIR(y, 2, 3)
    ACC_PAIR(z, 4, 5)
    ACC_PAIR(w, 6, 7)
#undef ACC_PAIR
}

static __device__ __forceinline__ void math_batch(
    float acc[8], const uint4 t[8], const Geom& g, int iy)
{
    acc8(acc, t[0], t[1], t[4], t[5], g.fx[0], g.fy[iy], g.vy[iy] * g.vx[0]);
    acc8(acc, t[2], t[3], t[6], t[7], g.fx[1], g.fy[iy], g.vy[iy] * g.vx[1]);
}

// ---------------- Phase 2: ROI gather from NHWC bf16 ----------------
// grid (R, 2). Block = half ROI (128 ch). 16-lane group per cell;
// lane = 8 channels (16 B taps). Software-pipelined A/B cell batches.
__global__ __launch_bounds__(512, 4) void roi_gather_nhwc(
    const unsigned short* __restrict__ feat_nhwc,
    const float* __restrict__ boxes,
    float* __restrict__ out, int R)
{
    __shared__ alignas(16) float lds[C_HALF * CSTRIDE];   // 28,672 B
    int r = blockIdx.x;
    if (r >= R) return;
    int chalf = blockIdx.y;            // 0 or 1: channel half
    int tid = threadIdx.x;
    int grp = tid >> 4;                // 0..31, cell group
    int ln  = tid & 15;                // channel octet index within half
    int swz = ln & 7;                  // == (c_local>>3)&7 for c_local = 8*ln+j

    const float* box = boxes + r * 5;
    int   b  = (int)box[0];
    float x1 = box[1] * SCALE;
    float y1 = box[2] * SCALE;
    float x2 = box[3] * SCALE;
    float y2 = box[4] * SCALE;
    float bin_w = fmaxf(x2 - x1, 1.0f) * (1.0f / PW);
    float bin_h = fmaxf(y2 - y1, 1.0f) * (1.0f / PH);

    // lane covers channels chalf*128 + 8*ln .. +7
    const unsigned short* fb = feat_nhwc + (size_t)b * HW * C_CH
                             + chalf * C_HALF + 8 * ln;

    int cellA = grp;                   // 0..31
    int cellB = grp + 32;              // 32..63; valid if < 49
    bool hasB = (cellB < CELLS);

    Geom gA, gB;
    geom_cell(gA, cellA, x1, y1, bin_w, bin_h);
    if (hasB) geom_cell(gB, cellB, x1, y1, bin_w, bin_h);

    // --- software pipeline: LA0 LA1 MA0 LB0 MA1 LB1 MB0 MB1 ---
    uint4 a0[8], a1[8];
    load_batch(a0, fb, gA, 0);
    load_batch(a1, fb, gA, 1);

    float accA[8] = {0.f, 0.f, 0.f, 0.f, 0.f, 0.f, 0.f, 0.f};
    math_batch(accA, a0, gA, 0);       // waits only on a0; a1 stays in flight

    uint4 b0[8];
    if (hasB) load_batch(b0, fb, gB, 0);

    math_batch(accA, a1, gA, 1);

    uint4 b1[8];
    if (hasB) load_batch(b1, fb, gB, 1);

    // --- swizzled LDS staging: [c_local][CSTRIDE], cell ^ ((c>>3)&7) ---
    {
        int cellx = cellA ^ swz;       // max 48^7 = 55 < CSTRIDE=56
#pragma unroll
        for (int j = 0; j < 8; ++j)
            lds[(8 * ln + j) * CSTRIDE + cellx] = accA[j] * 0.25f;
    }

    if (hasB) {
        float accB[8] = {0.f, 0.f, 0.f, 0.f, 0.f, 0.f, 0.f, 0.f};
        math_batch(accB, b0, gB, 0);
        math_batch(accB, b1, gB, 1);
        int cellx = cellB ^ swz;
#pragma unroll
        for (int j = 0; j < 8; ++j)
            lds[(8 * ln + j) * CSTRIDE + cellx] = accB[j] * 0.25f;
    }
    __syncthreads();

    // this block's output = 6272 contiguous floats at out[r][chalf*128][0]
    v4f* dst = (v4f*)(out + (size_t)r * (C_CH * CELLS) + chalf * (C_HALF * CELLS));
    for (int q = tid; q < (C_HALF * CELLS) / 4; q += 512) {
        int w0 = 4 * q;
        v4f v;
        {
            int c = w0 / 49, ce = w0 - 49 * c;
            v.x = lds[c * CSTRIDE + (ce ^ ((c >> 3) & 7))];
        }
        {
            int wv = w0 + 1; int c = wv / 49, ce = wv - 49 * c;
            v.y = lds[c * CSTRIDE + (ce ^ ((c >> 3) & 7))];
        }
        {
            int wv = w0 + 2; int c = wv / 49, ce = wv - 49 * c;
            v.z = lds[c * CSTRIDE + (ce ^ ((c >> 3) & 7))];
        }
        {
            int wv = w0 + 3; int c = wv / 49, ce = wv - 49 * c;
            v.w = lds[c * CSTRIDE + (ce ^ ((c >> 3) & 7))];
        }
        __builtin_nontemporal_store(v, dst + q);
    }
}

// ---------------- Fallback (round-1 kernel, NCHW fp32 direct) ----------------
__global__ __launch_bounds__(256) void roi_align_fallback(
    const float* __restrict__ feat,
    const float* __restrict__ boxes,
    float* __restrict__ out, int total)
{
    int idx = blockIdx.x * 256 + threadIdx.x;
    if (idx >= total) return;
    int pw = idx % PW;
    int t  = idx / PW;
    int ph = t % PH;
    t /= PH;
    int c = t & (C_CH - 1);
    int r = t >> 8;

    const float* box = boxes + r * 5;
    int   b  = (int)box[0];
    float x1 = box[1] * SCALE;
    float y1 = box[2] * SCALE;
    float x2 = box[3] * SCALE;
    float y2 = box[4] * SCALE;
    float bin_w = fmaxf(x2 - x1, 1.0f) * (1.0f / PW);
    float bin_h = fmaxf(y2 - y1, 1.0f) * (1.0f / PH);
    const float* fp = feat + ((size_t)b * C_CH + c) * HW;

    float acc = 0.0f;
#pragma unroll
    for (int iy = 0; iy < 2; ++iy) {
        float y = y1 + ((float)ph + (iy ? 0.75f : 0.25f)) * bin_h;
        bool vy = (y >= -1.0f) && (y <= (float)H_F);
        float cy = fmaxf(y, 0.0f);
        int ylr = (int)floorf(cy);
        int yl, yh; float fyv;
        if (ylr >= H_F - 1) { yl = H_F - 1; yh = H_F - 1; fyv = 0.0f; }
        else                { yl = ylr;     yh = ylr + 1; fyv = cy - (float)ylr; }
#pragma unroll
        for (int ix = 0; ix < 2; ++ix) {
            float x = x1 + ((float)pw + (ix ? 0.75f : 0.25f)) * bin_w;
            bool vx = (x >= -1.0f) && (x <= (float)W_F);
            float cx = fmaxf(x, 0.0f);
            int xlr = (int)floorf(cx);
            int xlv, xhv; float fxv;
            if (xlr >= W_F - 1) { xlv = W_F - 1; xhv = W_F - 1; fxv = 0.0f; }
            else                { xlv = xlr;     xhv = xlr + 1; fxv = cx - (float)xlr; }
            if (vy && vx) {
                const float* rl = fp + yl * W_F;
                const float* rh = fp + yh * W_F;
                float vll = rl[xlv], vlh = rl[xhv], vhl = rh[xlv], vhh = rh[xhv];
                float vlo = vll + fxv * (vlh - vll);
                float vhi = vhl + fxv * (vhh - vhl);
                acc += vlo + fyv * (vhi - vlo);
            }
        }
    }
    out[idx] = acc * 0.25f;
}

extern "C" void kernel_launch(void* const* d_in, const int* in_sizes, int n_in,
                              void* d_out, int out_size, void* d_ws, size_t ws_size,
                              hipStream_t stream) {
    const float* feat  = (const float*)d_in[0];
    const float* boxes = (const float*)d_in[1];
    float* out = (float*)d_out;
    int R = in_sizes[1] / 5;

    size_t need = (size_t)N_B * C_CH * HW * sizeof(unsigned short);  // 62.3 MB
    if (ws_size >= need) {
        unsigned short* nhwc = (unsigned short*)d_ws;
        dim3 tg(HW / 64, C_CH / 64, N_B);   // (950, 4, 2)
        transpose_nchw_nhwc_bf16<<<tg, 256, 0, stream>>>(feat, nhwc);
        dim3 gg(R, 2);                       // (1000, 2): half-ROI blocks
        roi_gather_nhwc<<<gg, 512, 0, stream>>>(nhwc, boxes, out, R);
    } else {
        int total = out_size;
        roi_align_fallback<<<(total + 255) / 256, 256, 0, stream>>>(feat, boxes, out, total);
    }
}

// Round 5
// 235.372 us; speedup vs baseline: 1.1496x; 1.1496x over previous
//
#include <hip/hip_runtime.h>
#include <hip/hip_bf16.h>

// ROI Align (torchvision semantics), fp32 in/out, two-phase with BF16 staging:
//   Phase 1: NCHW fp32 -> NHWC bf16 transpose (nontemporal float4 loads,
//            ushort4 stores).
//   Phase 2: gather; block = 512 thr = ONE ROI (all 256 channels).
//            Lane covers 8 consecutive channels (uint4 tap = 16 B/lane,
//            32-lane groups, 16 cells in flight).
//            BRANCHLESS: all taps loaded unconditionally (clamped indices
//            always in-range), invalid samples zeroed by weight.
//            fp32 results staged in LDS [c][56] with cell ^ ((c>>3)&7)
//            swizzle -> ~4-way banked writes instead of 16-way.
//            Flush = contiguous TEMPORAL float4 stores (NT stores measured
//            4.1x HBM write amplification: 205 MB vs 50 MB output — r4 PMC).
// Fallback: if ws_size too small, round-1 NCHW fp32 kernel (exact).

constexpr int N_B  = 2;
constexpr int C_CH = 256;
constexpr int H_F  = 200;
constexpr int W_F  = 304;
constexpr int HW   = H_F * W_F;        // 60800 = 64 * 950
constexpr int PH   = 7;
constexpr int PW   = 7;
constexpr int CELLS = PH * PW;         // 49
constexpr int CSTRIDE = 56;            // padded cell stride; holds cell^7 <= 55
constexpr float SCALE = 0.25f;

// native vector type for nontemporal load builtin (HIP_vector_type rejected)
typedef float  v4f __attribute__((ext_vector_type(4)));

static __device__ __forceinline__ unsigned short f2bf(float f) {
    __hip_bfloat16 h = __float2bfloat16(f);   // round-to-nearest-even
    return *reinterpret_cast<unsigned short*>(&h);
}
static __device__ __forceinline__ float blo(unsigned int u) {
    return __uint_as_float(u << 16);          // even channel (low short)
}
static __device__ __forceinline__ float bhi(unsigned int u) {
    return __uint_as_float(u & 0xffff0000u);  // odd channel (high short)
}

// ---------------- Phase 1: NCHW fp32 -> NHWC bf16 ----------------
// grid (HW/64=950, C/64=4, N=2), block 256.
__global__ __launch_bounds__(256) void transpose_nchw_nhwc_bf16(
    const float* __restrict__ in, unsigned short* __restrict__ out)
{
    __shared__ float tile[64][65];
    int tx = blockIdx.x * 64;          // HW base
    int ty = blockIdx.y * 64;          // C base
    int n  = blockIdx.z;
    const float* ip = in  + (size_t)n * C_CH * HW;
    unsigned short* op = out + (size_t)n * HW * C_CH;

    int w4 = threadIdx.x & 15;         // HW quad index
    int cr = threadIdx.x >> 4;         // 0..15
#pragma unroll
    for (int p = 0; p < 4; ++p) {
        int c = p * 16 + cr;
        // read-once: bypass-cache hint keeps LLC space for the bf16 buffer
        v4f v = __builtin_nontemporal_load(
            (const v4f*)&ip[(size_t)(ty + c) * HW + tx + 4 * w4]);
        tile[c][4 * w4 + 0] = v.x;
        tile[c][4 * w4 + 1] = v.y;
        tile[c][4 * w4 + 2] = v.z;
        tile[c][4 * w4 + 3] = v.w;
    }
    __syncthreads();
    int cq = threadIdx.x & 15;         // channel quad index
    int hr = threadIdx.x >> 4;         // 0..15
#pragma unroll
    for (int p = 0; p < 4; ++p) {
        int hw = p * 16 + hr;
        ushort4 v;
        v.x = f2bf(tile[4 * cq + 0][hw]);
        v.y = f2bf(tile[4 * cq + 1][hw]);
        v.z = f2bf(tile[4 * cq + 2][hw]);
        v.w = f2bf(tile[4 * cq + 3][hw]);
        *(ushort4*)&op[(size_t)(tx + hw) * C_CH + ty + 4 * cq] = v;
    }
}

// --- bilinear accumulate: 8 channels packed in uint4 (2 bf16 per uint) ---
static __device__ __forceinline__ void acc8(
    float* acc, uint4 ll, uint4 lh, uint4 hl, uint4 hh,
    float fxx, float fyy, float w)
{
#define ACC_PAIR(C, I0, I1)                                                   \
    { float a = blo(ll.C), b = blo(lh.C), c = blo(hl.C), d = blo(hh.C);       \
      float lo = a + fxx * (b - a), hi = c + fxx * (d - c);                   \
      acc[I0] += w * (lo + fyy * (hi - lo)); }                                \
    { float a = bhi(ll.C), b = bhi(lh.C), c = bhi(hl.C), d = bhi(hh.C);       \
      float lo = a + fxx * (b - a), hi = c + fxx * (d - c);                   \
      acc[I1] += w * (lo + fyy * (hi - lo)); }
    ACC_PAIR(x, 0, 1)
    ACC_PAIR(y, 2, 3)
    ACC_PAIR(z, 4, 5)
    ACC_PAIR(w, 6, 7)
#undef ACC_PAIR
}

// ---------------- Phase 2: ROI gather from NHWC bf16 ----------------
// One block per ROI. 512 thr; 32-lane group per cell; lane = 8 channels.
__global__ __launch_bounds__(512) void roi_gather_nhwc(
    const unsigned short* __restrict__ feat_nhwc,
    const float* __restrict__ boxes,
    float* __restrict__ out, int R)
{
    __shared__ alignas(16) float lds[C_CH * CSTRIDE];   // 57,344 B
    int r = blockIdx.x;
    if (r >= R) return;
    int tid = threadIdx.x;
    int grp = tid >> 5;                // 0..15, cell group
    int ln  = tid & 31;                // channel octet index
    int swz = ln & 7;                  // == (c>>3)&7 for c = 8*ln+j

    const float* box = boxes + r * 5;
    int   b  = (int)box[0];
    float x1 = box[1] * SCALE;
    float y1 = box[2] * SCALE;
    float x2 = box[3] * SCALE;
    float y2 = box[4] * SCALE;
    float bin_w = fmaxf(x2 - x1, 1.0f) * (1.0f / PW);
    float bin_h = fmaxf(y2 - y1, 1.0f) * (1.0f / PH);

    // lane covers channels 8*ln .. 8*ln+7
    const unsigned short* fb = feat_nhwc + (size_t)b * HW * C_CH + 8 * ln;

    for (int cell = grp; cell < CELLS; cell += 16) {
        int ph = cell / PW;
        int pw = cell - ph * PW;

        // --- geometry (branchless; clamped indices always in-range) ---
        int   yl[2], yh[2]; float fy[2], vy[2];
#pragma unroll
        for (int iy = 0; iy < 2; ++iy) {
            float y = y1 + ((float)ph + (iy ? 0.75f : 0.25f)) * bin_h;
            vy[iy] = (y >= -1.0f && y <= (float)H_F) ? 1.0f : 0.0f;
            float cy = fmaxf(y, 0.0f);
            int ylr = (int)floorf(cy);
            bool e = (ylr >= H_F - 1);
            yl[iy] = e ? H_F - 1 : ylr;
            yh[iy] = e ? H_F - 1 : ylr + 1;
            fy[iy] = e ? 0.0f : cy - (float)ylr;
        }
        int   xl[2], xh[2]; float fx[2], vx[2];
#pragma unroll
        for (int ix = 0; ix < 2; ++ix) {
            float x = x1 + ((float)pw + (ix ? 0.75f : 0.25f)) * bin_w;
            vx[ix] = (x >= -1.0f && x <= (float)W_F) ? 1.0f : 0.0f;
            float cx = fmaxf(x, 0.0f);
            int xlr = (int)floorf(cx);
            bool e = (xlr >= W_F - 1);
            xl[ix] = e ? W_F - 1 : xlr;
            xh[ix] = e ? W_F - 1 : xlr + 1;
            fx[ix] = e ? 0.0f : cx - (float)xlr;
        }

        float acc[8] = {0.f, 0.f, 0.f, 0.f, 0.f, 0.f, 0.f, 0.f};

        // --- per y-sample: 8 independent 16 B tap loads, then math ---
#pragma unroll
        for (int iy = 0; iy < 2; ++iy) {
            const unsigned short* rl = fb + (size_t)(yl[iy] * W_F) * C_CH;
            const unsigned short* rh = fb + (size_t)(yh[iy] * W_F) * C_CH;
            uint4 l0 = *(const uint4*)(rl + (size_t)xl[0] * C_CH);
            uint4 l1 = *(const uint4*)(rl + (size_t)xh[0] * C_CH);
            uint4 l2 = *(const uint4*)(rl + (size_t)xl[1] * C_CH);
            uint4 l3 = *(const uint4*)(rl + (size_t)xh[1] * C_CH);
            uint4 h0 = *(const uint4*)(rh + (size_t)xl[0] * C_CH);
            uint4 h1 = *(const uint4*)(rh + (size_t)xh[0] * C_CH);
            uint4 h2 = *(const uint4*)(rh + (size_t)xl[1] * C_CH);
            uint4 h3 = *(const uint4*)(rh + (size_t)xh[1] * C_CH);
            acc8(acc, l0, l1, h0, h1, fx[0], fy[iy], vy[iy] * vx[0]);
            acc8(acc, l2, l3, h2, h3, fx[1], fy[iy], vy[iy] * vx[1]);
        }

        // --- swizzled LDS staging: [c][CSTRIDE], cell ^ ((c>>3)&7) ---
        int cellx = cell ^ swz;        // max 48^7 = 55 < CSTRIDE=56
#pragma unroll
        for (int j = 0; j < 8; ++j)
            lds[(8 * ln + j) * CSTRIDE + cellx] = acc[j] * 0.25f;
    }
    __syncthreads();

    // out[r] = 12544 contiguous floats, channel-major (c*49 + cell)
    // TEMPORAL stores: coalesce to full lines in L2 (NT stores cost 4x HBM).
    float4* dst = (float4*)(out + (size_t)r * (C_CH * CELLS));
    for (int q = tid; q < (C_CH * CELLS) / 4; q += 512) {
        int w0 = 4 * q;
        float4 v;
        {
            int c = w0 / 49, ce = w0 - 49 * c;
            v.x = lds[c * CSTRIDE + (ce ^ ((c >> 3) & 7))];
        }
        {
            int wv = w0 + 1; int c = wv / 49, ce = wv - 49 * c;
            v.y = lds[c * CSTRIDE + (ce ^ ((c >> 3) & 7))];
        }
        {
            int wv = w0 + 2; int c = wv / 49, ce = wv - 49 * c;
            v.z = lds[c * CSTRIDE + (ce ^ ((c >> 3) & 7))];
        }
        {
            int wv = w0 + 3; int c = wv / 49, ce = wv - 49 * c;
            v.w = lds[c * CSTRIDE + (ce ^ ((c >> 3) & 7))];
        }
        dst[q] = v;
    }
}

// ---------------- Fallback (round-1 kernel, NCHW fp32 direct) ----------------
__global__ __launch_bounds__(256) void roi_align_fallback(
    const float* __restrict__ feat,
    const float* __restrict__ boxes,
    float* __restrict__ out, int total)
{
    int idx = blockIdx.x * 256 + threadIdx.x;
    if (idx >= total) return;
    int pw = idx % PW;
    int t  = idx / PW;
    int ph = t % PH;
    t /= PH;
    int c = t & (C_CH - 1);
    int r = t >> 8;

    const float* box = boxes + r * 5;
    int   b  = (int)box[0];
    float x1 = box[1] * SCALE;
    float y1 = box[2] * SCALE;
    float x2 = box[3] * SCALE;
    float y2 = box[4] * SCALE;
    float bin_w = fmaxf(x2 - x1, 1.0f) * (1.0f / PW);
    float bin_h = fmaxf(y2 - y1, 1.0f) * (1.0f / PH);
    const float* fp = feat + ((size_t)b * C_CH + c) * HW;

    float acc = 0.0f;
#pragma unroll
    for (int iy = 0; iy < 2; ++iy) {
        float y = y1 + ((float)ph + (iy ? 0.75f : 0.25f)) * bin_h;
        bool vy = (y >= -1.0f) && (y <= (float)H_F);
        float cy = fmaxf(y, 0.0f);
        int ylr = (int)floorf(cy);
        int yl, yh; float fyv;
        if (ylr >= H_F - 1) { yl = H_F - 1; yh = H_F - 1; fyv = 0.0f; }
        else                { yl = ylr;     yh = ylr + 1; fyv = cy - (float)ylr; }
#pragma unroll
        for (int ix = 0; ix < 2; ++ix) {
            float x = x1 + ((float)pw + (ix ? 0.75f : 0.25f)) * bin_w;
            bool vx = (x >= -1.0f) && (x <= (float)W_F);
            float cx = fmaxf(x, 0.0f);
            int xlr = (int)floorf(cx);
            int xlv, xhv; float fxv;
            if (xlr >= W_F - 1) { xlv = W_F - 1; xhv = W_F - 1; fxv = 0.0f; }
            else                { xlv = xlr;     xhv = xlr + 1; fxv = cx - (float)xlr; }
            if (vy && vx) {
                const float* rl = fp + yl * W_F;
                const float* rh = fp + yh * W_F;
                float vll = rl[xlv], vlh = rl[xhv], vhl = rh[xlv], vhh = rh[xhv];
                float vlo = vll + fxv * (vlh - vll);
                float vhi = vhl + fxv * (vhh - vhl);
                acc += vlo + fyv * (vhi - vlo);
            }
        }
    }
    out[idx] = acc * 0.25f;
}

extern "C" void kernel_launch(void* const* d_in, const int* in_sizes, int n_in,
                              void* d_out, int out_size, void* d_ws, size_t ws_size,
                              hipStream_t stream) {
    const float* feat  = (const float*)d_in[0];
    const float* boxes = (const float*)d_in[1];
    float* out = (float*)d_out;
    int R = in_sizes[1] / 5;

    size_t need = (size_t)N_B * C_CH * HW * sizeof(unsigned short);  // 62.3 MB
    if (ws_size >= need) {
        unsigned short* nhwc = (unsigned short*)d_ws;
        dim3 tg(HW / 64, C_CH / 64, N_B);   // (950, 4, 2)
        transpose_nchw_nhwc_bf16<<<tg, 256, 0, stream>>>(feat, nhwc);
        roi_gather_nhwc<<<R, 512, 0, stream>>>(nhwc, boxes, out, R);
    } else {
        int total = out_size;
        roi_align_fallback<<<(total + 255) / 256, 256, 0, stream>>>(feat, boxes, out, total);
    }
}

// Round 6
// 229.434 us; speedup vs baseline: 1.1793x; 1.0259x over previous
//
#include <hip/hip_runtime.h>
#include <hip/hip_bf16.h>

// ROI Align (torchvision semantics), fp32 in/out, three-phase:
//   Phase 0: spatial ROI sort (1 block, bitonic over <=1024 keys):
//            key = (batch, 16-row y-stripe, serpentine x). Written to perm[]
//            in ws. Gather applies XCD-chunk swizzle (bid%8)*R/8+bid/8 so
//            each XCD processes ~R/8 spatially-contiguous ROIs -> tap reuse
//            is served by that XCD's 4 MB L2 instead of MALL/HBM
//            (r4 PMC: FETCH_SIZE=165 MB vs 62 MB feature = 2.6x over-fetch).
//   Phase 1: NCHW fp32 -> NHWC bf16 transpose (nontemporal float4 loads,
//            ushort4 stores). ~31 us, at its 187 MB roofline.
//   Phase 2: gather; block = 512 thr = ONE ROI (all 256 channels).
//            Lane covers 8 consecutive channels (uint4 tap = 16 B/lane,
//            32-lane groups, 16 cells in flight). BRANCHLESS taps, invalid
//            samples zeroed by weight. LDS staging [c][56] with
//            cell ^ ((c>>3)&7) swizzle; contiguous temporal float4 flush.
// Fallback: if ws_size too small, round-1 NCHW fp32 kernel (exact).

constexpr int N_B  = 2;
constexpr int C_CH = 256;
constexpr int H_F  = 200;
constexpr int W_F  = 304;
constexpr int HW   = H_F * W_F;        // 60800 = 64 * 950
constexpr int PH   = 7;
constexpr int PW   = 7;
constexpr int CELLS = PH * PW;         // 49
constexpr int CSTRIDE = 56;            // padded cell stride; holds cell^7 <= 55
constexpr int NXCD = 8;
constexpr float SCALE = 0.25f;

// native vector type for nontemporal load builtin (HIP_vector_type rejected)
typedef float  v4f __attribute__((ext_vector_type(4)));

static __device__ __forceinline__ unsigned short f2bf(float f) {
    __hip_bfloat16 h = __float2bfloat16(f);   // round-to-nearest-even
    return *reinterpret_cast<unsigned short*>(&h);
}
static __device__ __forceinline__ float blo(unsigned int u) {
    return __uint_as_float(u << 16);          // even channel (low short)
}
static __device__ __forceinline__ float bhi(unsigned int u) {
    return __uint_as_float(u & 0xffff0000u);  // odd channel (high short)
}

// ---------------- Phase 0: spatial ROI sort ----------------
// One block, 1024 threads. Bitonic sort of packed (spatial_key<<10 | idx).
__global__ __launch_bounds__(1024) void sort_rois(
    const float* __restrict__ boxes, unsigned int* __restrict__ perm, int R)
{
    int t = threadIdx.x;
    if (R > 1024) {                    // fallback: identity permutation
        for (int i = t; i < R; i += 1024) perm[i] = (unsigned int)i;
        return;
    }
    __shared__ unsigned int k[1024];
    unsigned int key = 0xFFFFFFFFu;    // padding sorts to the end
    if (t < R) {
        const float* box = boxes + t * 5;
        int b  = (int)box[0];
        float yc = (box[2] + box[4]) * 0.5f * SCALE;
        float xc = (box[1] + box[3]) * 0.5f * SCALE;
        int yq = min(max((int)yc, 0), H_F - 1);
        int xq = min(max((int)xc, 0), W_F - 1);
        int stripe = yq >> 4;          // 16-row stripes: 0..12 (4 bits)
        int xs = (stripe & 1) ? (W_F - 1 - xq) : xq;   // serpentine (9 bits)
        unsigned int s = ((unsigned int)b << 13) | ((unsigned int)stripe << 9)
                       | (unsigned int)xs;
        key = (s << 10) | (unsigned int)t;             // idx in low 10 bits
    }
    k[t] = key;
    __syncthreads();
#pragma unroll 1
    for (int size = 2; size <= 1024; size <<= 1) {
#pragma unroll 1
        for (int stride = size >> 1; stride > 0; stride >>= 1) {
            int j = t ^ stride;
            if (j > t) {
                unsigned int a = k[t], c = k[j];
                bool up = ((t & size) == 0);
                if ((a > c) == up) { k[t] = c; k[j] = a; }
            }
            __syncthreads();
        }
    }
    if (t < R) perm[t] = k[t] & 1023u;
}

// ---------------- Phase 1: NCHW fp32 -> NHWC bf16 ----------------
// grid (HW/64=950, C/64=4, N=2), block 256.
__global__ __launch_bounds__(256) void transpose_nchw_nhwc_bf16(
    const float* __restrict__ in, unsigned short* __restrict__ out)
{
    __shared__ float tile[64][65];
    int tx = blockIdx.x * 64;          // HW base
    int ty = blockIdx.y * 64;          // C base
    int n  = blockIdx.z;
    const float* ip = in  + (size_t)n * C_CH * HW;
    unsigned short* op = out + (size_t)n * HW * C_CH;

    int w4 = threadIdx.x & 15;         // HW quad index
    int cr = threadIdx.x >> 4;         // 0..15
#pragma unroll
    for (int p = 0; p < 4; ++p) {
        int c = p * 16 + cr;
        // read-once: bypass-cache hint keeps LLC space for the bf16 buffer
        v4f v = __builtin_nontemporal_load(
            (const v4f*)&ip[(size_t)(ty + c) * HW + tx + 4 * w4]);
        tile[c][4 * w4 + 0] = v.x;
        tile[c][4 * w4 + 1] = v.y;
        tile[c][4 * w4 + 2] = v.z;
        tile[c][4 * w4 + 3] = v.w;
    }
    __syncthreads();
    int cq = threadIdx.x & 15;         // channel quad index
    int hr = threadIdx.x >> 4;         // 0..15
#pragma unroll
    for (int p = 0; p < 4; ++p) {
        int hw = p * 16 + hr;
        ushort4 v;
        v.x = f2bf(tile[4 * cq + 0][hw]);
        v.y = f2bf(tile[4 * cq + 1][hw]);
        v.z = f2bf(tile[4 * cq + 2][hw]);
        v.w = f2bf(tile[4 * cq + 3][hw]);
        *(ushort4*)&op[(size_t)(tx + hw) * C_CH + ty + 4 * cq] = v;
    }
}

// --- bilinear accumulate: 8 channels packed in uint4 (2 bf16 per uint) ---
static __device__ __forceinline__ void acc8(
    float* acc, uint4 ll, uint4 lh, uint4 hl, uint4 hh,
    float fxx, float fyy, float w)
{
#define ACC_PAIR(C, I0, I1)                                                   \
    { float a = blo(ll.C), b = blo(lh.C), c = blo(hl.C), d = blo(hh.C);       \
      float lo = a + fxx * (b - a), hi = c + fxx * (d - c);                   \
      acc[I0] += w * (lo + fyy * (hi - lo)); }                                \
    { float a = bhi(ll.C), b = bhi(lh.C), c = bhi(hl.C), d = bhi(hh.C);       \
      float lo = a + fxx * (b - a), hi = c + fxx * (d - c);                   \
      acc[I1] += w * (lo + fyy * (hi - lo)); }
    ACC_PAIR(x, 0, 1)
    ACC_PAIR(y, 2, 3)
    ACC_PAIR(z, 4, 5)
    ACC_PAIR(w, 6, 7)
#undef ACC_PAIR
}

// ---------------- Phase 2: ROI gather from NHWC bf16 ----------------
// One block per (sorted) ROI. 512 thr; 32-lane group per cell; lane = 8 ch.
__global__ __launch_bounds__(512) void roi_gather_nhwc(
    const unsigned short* __restrict__ feat_nhwc,
    const float* __restrict__ boxes,
    const unsigned int* __restrict__ perm,
    float* __restrict__ out, int R)
{
    __shared__ alignas(16) float lds[C_CH * CSTRIDE];   // 57,344 B
    int pos = blockIdx.x;
    if (pos >= R) return;
    // XCD-chunk swizzle: XCD k gets sorted positions [k*R/8, (k+1)*R/8)
    if ((R & (NXCD - 1)) == 0) {
        int cpx = R / NXCD;
        pos = (pos & (NXCD - 1)) * cpx + (pos >> 3);
    }
    int r = (int)perm[pos];
    if (r >= R) return;                 // safety (padding can't reach here)

    int tid = threadIdx.x;
    int grp = tid >> 5;                // 0..15, cell group
    int ln  = tid & 31;                // channel octet index
    int swz = ln & 7;                  // == (c>>3)&7 for c = 8*ln+j

    const float* box = boxes + r * 5;
    int   b  = (int)box[0];
    float x1 = box[1] * SCALE;
    float y1 = box[2] * SCALE;
    float x2 = box[3] * SCALE;
    float y2 = box[4] * SCALE;
    float bin_w = fmaxf(x2 - x1, 1.0f) * (1.0f / PW);
    float bin_h = fmaxf(y2 - y1, 1.0f) * (1.0f / PH);

    // lane covers channels 8*ln .. 8*ln+7
    const unsigned short* fb = feat_nhwc + (size_t)b * HW * C_CH + 8 * ln;

    for (int cell = grp; cell < CELLS; cell += 16) {
        int ph = cell / PW;
        int pw = cell - ph * PW;

        // --- geometry (branchless; clamped indices always in-range) ---
        int   yl[2], yh[2]; float fy[2], vy[2];
#pragma unroll
        for (int iy = 0; iy < 2; ++iy) {
            float y = y1 + ((float)ph + (iy ? 0.75f : 0.25f)) * bin_h;
            vy[iy] = (y >= -1.0f && y <= (float)H_F) ? 1.0f : 0.0f;
            float cy = fmaxf(y, 0.0f);
            int ylr = (int)floorf(cy);
            bool e = (ylr >= H_F - 1);
            yl[iy] = e ? H_F - 1 : ylr;
            yh[iy] = e ? H_F - 1 : ylr + 1;
            fy[iy] = e ? 0.0f : cy - (float)ylr;
        }
        int   xl[2], xh[2]; float fx[2], vx[2];
#pragma unroll
        for (int ix = 0; ix < 2; ++ix) {
            float x = x1 + ((float)pw + (ix ? 0.75f : 0.25f)) * bin_w;
            vx[ix] = (x >= -1.0f && x <= (float)W_F) ? 1.0f : 0.0f;
            float cx = fmaxf(x, 0.0f);
            int xlr = (int)floorf(cx);
            bool e = (xlr >= W_F - 1);
            xl[ix] = e ? W_F - 1 : xlr;
            xh[ix] = e ? W_F - 1 : xlr + 1;
            fx[ix] = e ? 0.0f : cx - (float)xlr;
        }

        float acc[8] = {0.f, 0.f, 0.f, 0.f, 0.f, 0.f, 0.f, 0.f};

        // --- per y-sample: 8 independent 16 B tap loads, then math ---
#pragma unroll
        for (int iy = 0; iy < 2; ++iy) {
            const unsigned short* rl = fb + (size_t)(yl[iy] * W_F) * C_CH;
            const unsigned short* rh = fb + (size_t)(yh[iy] * W_F) * C_CH;
            uint4 l0 = *(const uint4*)(rl + (size_t)xl[0] * C_CH);
            uint4 l1 = *(const uint4*)(rl + (size_t)xh[0] * C_CH);
            uint4 l2 = *(const uint4*)(rl + (size_t)xl[1] * C_CH);
            uint4 l3 = *(const uint4*)(rl + (size_t)xh[1] * C_CH);
            uint4 h0 = *(const uint4*)(rh + (size_t)xl[0] * C_CH);
            uint4 h1 = *(const uint4*)(rh + (size_t)xh[0] * C_CH);
            uint4 h2 = *(const uint4*)(rh + (size_t)xl[1] * C_CH);
            uint4 h3 = *(const uint4*)(rh + (size_t)xh[1] * C_CH);
            acc8(acc, l0, l1, h0, h1, fx[0], fy[iy], vy[iy] * vx[0]);
            acc8(acc, l2, l3, h2, h3, fx[1], fy[iy], vy[iy] * vx[1]);
        }

        // --- swizzled LDS staging: [c][CSTRIDE], cell ^ ((c>>3)&7) ---
        int cellx = cell ^ swz;        // max 48^7 = 55 < CSTRIDE=56
#pragma unroll
        for (int j = 0; j < 8; ++j)
            lds[(8 * ln + j) * CSTRIDE + cellx] = acc[j] * 0.25f;
    }
    __syncthreads();

    // out[r] = 12544 contiguous floats, channel-major (c*49 + cell)
    float4* dst = (float4*)(out + (size_t)r * (C_CH * CELLS));
    for (int q = tid; q < (C_CH * CELLS) / 4; q += 512) {
        int w0 = 4 * q;
        float4 v;
        {
            int c = w0 / 49, ce = w0 - 49 * c;
            v.x = lds[c * CSTRIDE + (ce ^ ((c >> 3) & 7))];
        }
        {
            int wv = w0 + 1; int c = wv / 49, ce = wv - 49 * c;
            v.y = lds[c * CSTRIDE + (ce ^ ((c >> 3) & 7))];
        }
        {
            int wv = w0 + 2; int c = wv / 49, ce = wv - 49 * c;
            v.z = lds[c * CSTRIDE + (ce ^ ((c >> 3) & 7))];
        }
        {
            int wv = w0 + 3; int c = wv / 49, ce = wv - 49 * c;
            v.w = lds[c * CSTRIDE + (ce ^ ((c >> 3) & 7))];
        }
        dst[q] = v;
    }
}

// ---------------- Fallback (round-1 kernel, NCHW fp32 direct) ----------------
__global__ __launch_bounds__(256) void roi_align_fallback(
    const float* __restrict__ feat,
    const float* __restrict__ boxes,
    float* __restrict__ out, int total)
{
    int idx = blockIdx.x * 256 + threadIdx.x;
    if (idx >= total) return;
    int pw = idx % PW;
    int t  = idx / PW;
    int ph = t % PH;
    t /= PH;
    int c = t & (C_CH - 1);
    int r = t >> 8;

    const float* box = boxes + r * 5;
    int   b  = (int)box[0];
    float x1 = box[1] * SCALE;
    float y1 = box[2] * SCALE;
    float x2 = box[3] * SCALE;
    float y2 = box[4] * SCALE;
    float bin_w = fmaxf(x2 - x1, 1.0f) * (1.0f / PW);
    float bin_h = fmaxf(y2 - y1, 1.0f) * (1.0f / PH);
    const float* fp = feat + ((size_t)b * C_CH + c) * HW;

    float acc = 0.0f;
#pragma unroll
    for (int iy = 0; iy < 2; ++iy) {
        float y = y1 + ((float)ph + (iy ? 0.75f : 0.25f)) * bin_h;
        bool vy = (y >= -1.0f) && (y <= (float)H_F);
        float cy = fmaxf(y, 0.0f);
        int ylr = (int)floorf(cy);
        int yl, yh; float fyv;
        if (ylr >= H_F - 1) { yl = H_F - 1; yh = H_F - 1; fyv = 0.0f; }
        else                { yl = ylr;     yh = ylr + 1; fyv = cy - (float)ylr; }
#pragma unroll
        for (int ix = 0; ix < 2; ++ix) {
            float x = x1 + ((float)pw + (ix ? 0.75f : 0.25f)) * bin_w;
            bool vx = (x >= -1.0f) && (x <= (float)W_F);
            float cx = fmaxf(x, 0.0f);
            int xlr = (int)floorf(cx);
            int xlv, xhv; float fxv;
            if (xlr >= W_F - 1) { xlv = W_F - 1; xhv = W_F - 1; fxv = 0.0f; }
            else                { xlv = xlr;     xhv = xlr + 1; fxv = cx - (float)xlr; }
            if (vy && vx) {
                const float* rl = fp + yl * W_F;
                const float* rh = fp + yh * W_F;
                float vll = rl[xlv], vlh = rl[xhv], vhl = rh[xlv], vhh = rh[xhv];
                float vlo = vll + fxv * (vlh - vll);
                float vhi = vhl + fxv * (vhh - vhl);
                acc += vlo + fyv * (vhi - vlo);
            }
        }
    }
    out[idx] = acc * 0.25f;
}

extern "C" void kernel_launch(void* const* d_in, const int* in_sizes, int n_in,
                              void* d_out, int out_size, void* d_ws, size_t ws_size,
                              hipStream_t stream) {
    const float* feat  = (const float*)d_in[0];
    const float* boxes = (const float*)d_in[1];
    float* out = (float*)d_out;
    int R = in_sizes[1] / 5;

    size_t need_nhwc = (size_t)N_B * C_CH * HW * sizeof(unsigned short);  // 62.3 MB
    size_t perm_off  = (need_nhwc + 255) & ~(size_t)255;
    size_t need      = perm_off + (size_t)((R > 1024 ? R : 1024)) * sizeof(unsigned int);
    if (ws_size >= need) {
        unsigned short* nhwc = (unsigned short*)d_ws;
        unsigned int*   perm = (unsigned int*)((char*)d_ws + perm_off);
        sort_rois<<<1, 1024, 0, stream>>>(boxes, perm, R);
        dim3 tg(HW / 64, C_CH / 64, N_B);   // (950, 4, 2)
        transpose_nchw_nhwc_bf16<<<tg, 256, 0, stream>>>(feat, nhwc);
        roi_gather_nhwc<<<R, 512, 0, stream>>>(nhwc, boxes, perm, out, R);
    } else {
        int total = out_size;
        roi_align_fallback<<<(total + 255) / 256, 256, 0, stream>>>(feat, boxes, out, total);
    }
}